// Round 1
// baseline (111.226 us; speedup 1.0000x reference)
//
#include <hip/hip_runtime.h>

#define BB 8
#define CC 64
#define NNN 4096
#define KK 20
#define MM 8
#define OC 64
#define CM 512

typedef __attribute__((ext_vector_type(8))) short bf16x8;
typedef __attribute__((ext_vector_type(4))) float f32x4;

__device__ __forceinline__ unsigned short f2bf(float f) {
    union { float f; unsigned int u; } v; v.f = f;
    unsigned int u = v.u;
    return (unsigned short)((u + 0x7FFFu + ((u >> 16) & 1u)) >> 16);
}

// Kernel 1: transpose feature (B,C,N)->(B,N,C) into ws; convert conv_w to bf16 [o][k]
__global__ __launch_bounds__(256) void prep_kernel(const float* __restrict__ feature,
                                                   const float* __restrict__ conv_w,
                                                   float* __restrict__ ftr,
                                                   unsigned short* __restrict__ Wb) {
    int blk = blockIdx.x;
    int t = threadIdx.x;
    if (blk < 512) {
        __shared__ float tile[64 * 65];
        int b = blk >> 6;
        int n0 = (blk & 63) << 6;
        const float* fb = feature + b * (CC * NNN);
        #pragma unroll
        for (int s = 0; s < 16; ++s) {
            int i = t + s * 256;
            int c = i >> 6, nn = i & 63;
            tile[c * 65 + nn] = fb[c * NNN + n0 + nn];
        }
        __syncthreads();
        float* fo = ftr + b * (NNN * CC) + n0 * CC;
        #pragma unroll
        for (int s = 0; s < 16; ++s) {
            int i = t + s * 256;
            int n = i >> 6, cc = i & 63;
            fo[n * CC + cc] = tile[cc * 65 + n];
        }
    } else {
        int base = (blk - 512) * 8192;
        #pragma unroll
        for (int s = 0; s < 32; ++s) {
            int i = base + t + s * 256;
            Wb[i] = f2bf(conv_w[i]);
        }
    }
}

// Kernel 2: per 16-point block: perm(softmax) -> agg -> mfma conv -> epilogue
__global__ __launch_bounds__(256) void main_kernel(
    const float* __restrict__ x,
    const float* __restrict__ feature,
    const int* __restrict__ nidx,
    const float* __restrict__ kern,
    const float* __restrict__ conv_b,
    const float* __restrict__ ftr,
    const unsigned short* __restrict__ Wb,
    float* __restrict__ out)
{
    __shared__ int idx_lds[16 * KK];                          // 1280 B
    __shared__ float xn_lds[16 * KK * 3];                     // 3840 B
    __shared__ __align__(16) float perm_lds[16 * KK * MM];    // 10240 B
    __shared__ __align__(16) unsigned short aggA[16 * 520];   // 16640 B (pad 512->520)

    int t = threadIdx.x;
    int blk = blockIdx.x;
    int b = blk >> 8;
    int n0 = (blk & 255) << 4;

    // stage neighbor indices
    const int* nb = nidx + (b * NNN + n0) * KK;
    for (int i = t; i < 16 * KK; i += 256) idx_lds[i] = nb[i];
    __syncthreads();

    // stage neighbor xyz
    const float* xb = x + b * (3 * NNN);
    for (int i = t; i < 16 * KK * 3; i += 256) {
        int p = i / 60;
        int rem = i - p * 60;
        int k = rem / 3;
        int c = rem - k * 3;
        xn_lds[i] = xb[c * NNN + idx_lds[p * KK + k]];
    }
    __syncthreads();

    // phase A: permatrix + softmax over k (thread = (point, m))
    if (t < 128) {
        int p = t >> 3;
        int m = t & 7;
        float k0 = kern[0 * MM + m], k1 = kern[1 * MM + m], k2 = kern[2 * MM + m];
        const float* xp = &xn_lds[p * 60];
        float bx = xp[0], by = xp[1], bz = xp[2];
        float pv[KK];
        #pragma unroll
        for (int k = 0; k < KK; ++k) {
            float dx = xp[k * 3 + 0] - bx;
            float dy = xp[k * 3 + 1] - by;
            float dz = xp[k * 3 + 2] - bz;
            pv[k] = dx * k0 + dy * k1 + dz * k2;
        }
        if (m == 0) pv[0] += 1.0f;   // one_pad[0,0]
        float mx = pv[0];
        #pragma unroll
        for (int k = 1; k < KK; ++k) mx = fmaxf(mx, pv[k]);
        float sum = 0.f;
        #pragma unroll
        for (int k = 0; k < KK; ++k) { pv[k] = __expf(pv[k] - mx); sum += pv[k]; }
        float inv = 1.0f / sum;
        #pragma unroll
        for (int k = 0; k < KK; ++k) perm_lds[(p * KK + k) * MM + m] = pv[k] * inv;
    }
    __syncthreads();

    // phase B: agg[p][c][m] = sum_k f[k][c] * perm[k][m]  (thread = (point, 4 c's))
    {
        int p = t >> 4;
        int cg = (t & 15) << 2;
        const float* fb = ftr + b * (NNN * CC);
        float acc[4][MM];
        #pragma unroll
        for (int ci = 0; ci < 4; ++ci)
            #pragma unroll
            for (int m = 0; m < MM; ++m) acc[ci][m] = 0.f;
        #pragma unroll 4
        for (int k = 0; k < KK; ++k) {
            int idx = idx_lds[p * KK + k];
            float4 f4 = *(const float4*)&fb[idx * CC + cg];
            float4 pm0 = *(const float4*)&perm_lds[(p * KK + k) * MM];
            float4 pm1 = *(const float4*)&perm_lds[(p * KK + k) * MM + 4];
            float fv[4] = {f4.x, f4.y, f4.z, f4.w};
            float pvv[8] = {pm0.x, pm0.y, pm0.z, pm0.w, pm1.x, pm1.y, pm1.z, pm1.w};
            #pragma unroll
            for (int ci = 0; ci < 4; ++ci)
                #pragma unroll
                for (int m = 0; m < MM; ++m)
                    acc[ci][m] += fv[ci] * pvv[m];
        }
        #pragma unroll
        for (int ci = 0; ci < 4; ++ci) {
            union { bf16x8 v; unsigned short s[8]; } u;
            #pragma unroll
            for (int m = 0; m < MM; ++m) u.s[m] = f2bf(acc[ci][m]);
            *(bf16x8*)&aggA[p * 520 + (cg + ci) * MM] = u.v;
        }
    }
    __syncthreads();

    // phase C: out[p][o] = lrelu(agg[p][:] . W[o][:] + b[o]) + feature ; wave w -> o-tile
    {
        int w = t >> 6;
        int l = t & 63;
        int o0 = w << 4;
        int row = l & 15;        // A-row (point) and B-col (o)
        int kg = (l >> 4) << 3;  // k sub-offset within 32-chunk
        f32x4 acc = {0.f, 0.f, 0.f, 0.f};
        const unsigned short* wrow = Wb + (o0 + row) * CM;
        const unsigned short* arow = aggA + row * 520;
        #pragma unroll
        for (int s = 0; s < 16; ++s) {
            int k = s * 32 + kg;
            bf16x8 af = *(const bf16x8*)&arow[k];
            bf16x8 bfr = *(const bf16x8*)&wrow[k];
            acc = __builtin_amdgcn_mfma_f32_16x16x32_bf16(af, bfr, acc, 0, 0, 0);
        }
        int o = o0 + row;
        float bias = conv_b[o];
        const float* fres = feature + b * (CC * NNN) + o * NNN + n0;
        float* op = out + b * (OC * NNN) + o * NNN + n0;
        #pragma unroll
        for (int r = 0; r < 4; ++r) {
            int pt = ((l >> 4) << 2) + r;   // C/D: row = (lane>>4)*4 + reg
            float v = acc[r] + bias;
            v = v > 0.f ? v : v * 0.2f;
            op[pt] = v + fres[pt];
        }
    }
}

extern "C" void kernel_launch(void* const* d_in, const int* in_sizes, int n_in,
                              void* d_out, int out_size, void* d_ws, size_t ws_size,
                              hipStream_t stream) {
    const float* x        = (const float*)d_in[0];
    const float* feature  = (const float*)d_in[1];
    const int*   nidx     = (const int*)d_in[2];
    const float* kern     = (const float*)d_in[3];
    const float* conv_w   = (const float*)d_in[4];
    const float* conv_b   = (const float*)d_in[5];
    float* out = (float*)d_out;

    float* ftr = (float*)d_ws;                                        // 8 MB: (B,N,C) f32
    unsigned short* Wb = (unsigned short*)((char*)d_ws + 8388608);    // 64 KB: bf16 W [o][k]

    prep_kernel<<<516, 256, 0, stream>>>(feature, conv_w, ftr, Wb);
    main_kernel<<<2048, 256, 0, stream>>>(x, feature, nidx, kern, conv_b, ftr, Wb, out);
}

// Round 2
// 109.665 us; speedup vs baseline: 1.0142x; 1.0142x over previous
//
#include <hip/hip_runtime.h>

#define BB 8
#define CC 64
#define NNN 4096
#define KK 20
#define MM 8
#define OC 64
#define CM 512

typedef __attribute__((ext_vector_type(8))) short bf16x8;
typedef __attribute__((ext_vector_type(4))) float f32x4;

__device__ __forceinline__ unsigned short f2bf(float f) {
    union { float f; unsigned int u; } v; v.f = f;
    unsigned int u = v.u;
    return (unsigned short)((u + 0x7FFFu + ((u >> 16) & 1u)) >> 16);
}
__device__ __forceinline__ float bfhi2f(unsigned int u) {  // high 16 bits
    union { unsigned int u; float f; } v; v.u = u & 0xffff0000u; return v.f;
}
__device__ __forceinline__ float bflo2f(unsigned int u) {  // low 16 bits
    union { unsigned int u; float f; } v; v.u = u << 16; return v.f;
}

// Kernel 1: transpose feature (B,C,N)->(B,N,C) bf16 into ws; conv_w -> bf16 [o][k]
// Block swizzle: b = blk & 7 so (round-robin) XCD x produces batch x's slice.
__global__ __launch_bounds__(256) void prep_kernel(const float* __restrict__ feature,
                                                   const float* __restrict__ conv_w,
                                                   unsigned short* __restrict__ ftr,
                                                   unsigned short* __restrict__ Wb) {
    int blk = blockIdx.x;
    int t = threadIdx.x;
    if (blk < 512) {
        __shared__ float tile[64 * 65];
        int b = blk & 7;
        int n0 = (blk >> 3) << 6;
        const float* fb = feature + b * (CC * NNN);
        #pragma unroll
        for (int s = 0; s < 16; ++s) {
            int i = t + s * 256;
            int c = i >> 6, nn = i & 63;
            tile[c * 65 + nn] = fb[c * NNN + n0 + nn];
        }
        __syncthreads();
        unsigned short* fo = ftr + b * (NNN * CC) + n0 * CC;
        #pragma unroll
        for (int s = 0; s < 16; ++s) {
            int i = t + s * 256;
            int n = i >> 6, cc = i & 63;
            fo[n * CC + cc] = f2bf(tile[cc * 65 + n]);
        }
    } else {
        int base = (blk - 512) * 8192;
        #pragma unroll
        for (int s = 0; s < 32; ++s) {
            int i = base + t + s * 256;
            Wb[i] = f2bf(conv_w[i]);
        }
    }
}

// Kernel 2: per 16-point block: perm(softmax) -> agg (bf16 gather) -> mfma conv -> epilogue
// Block swizzle: b = blk & 7 so consumers of batch b land on the XCD that produced it.
__global__ __launch_bounds__(256) void main_kernel(
    const float* __restrict__ x,
    const float* __restrict__ feature,
    const int* __restrict__ nidx,
    const float* __restrict__ kern,
    const float* __restrict__ conv_b,
    const unsigned short* __restrict__ ftr,
    const unsigned short* __restrict__ Wb,
    float* __restrict__ out)
{
    __shared__ int idx_lds[16 * KK];                          // 1280 B
    __shared__ float xn_lds[16 * KK * 3];                     // 3840 B
    __shared__ __align__(16) float perm_lds[16 * KK * MM];    // 10240 B
    __shared__ __align__(16) unsigned short aggA[16 * 520];   // 16640 B (pad 512->520)

    int t = threadIdx.x;
    int blk = blockIdx.x;
    int b = blk & 7;
    int n0 = (blk >> 3) << 4;

    // stage neighbor indices
    const int* nb = nidx + (b * NNN + n0) * KK;
    for (int i = t; i < 16 * KK; i += 256) idx_lds[i] = nb[i];
    __syncthreads();

    // stage neighbor xyz
    const float* xb = x + b * (3 * NNN);
    for (int i = t; i < 16 * KK * 3; i += 256) {
        int p = i / 60;
        int rem = i - p * 60;
        int k = rem / 3;
        int c = rem - k * 3;
        xn_lds[i] = xb[c * NNN + idx_lds[p * KK + k]];
    }
    __syncthreads();

    // phase A: permatrix + softmax over k (thread = (point, m))
    if (t < 128) {
        int p = t >> 3;
        int m = t & 7;
        float k0 = kern[0 * MM + m], k1 = kern[1 * MM + m], k2 = kern[2 * MM + m];
        const float* xp = &xn_lds[p * 60];
        float bx = xp[0], by = xp[1], bz = xp[2];
        float pv[KK];
        #pragma unroll
        for (int k = 0; k < KK; ++k) {
            float dx = xp[k * 3 + 0] - bx;
            float dy = xp[k * 3 + 1] - by;
            float dz = xp[k * 3 + 2] - bz;
            pv[k] = dx * k0 + dy * k1 + dz * k2;
        }
        if (m == 0) pv[0] += 1.0f;   // one_pad[0,0]
        float mx = pv[0];
        #pragma unroll
        for (int k = 1; k < KK; ++k) mx = fmaxf(mx, pv[k]);
        float sum = 0.f;
        #pragma unroll
        for (int k = 0; k < KK; ++k) { pv[k] = __expf(pv[k] - mx); sum += pv[k]; }
        float inv = 1.0f / sum;
        #pragma unroll
        for (int k = 0; k < KK; ++k) perm_lds[(p * KK + k) * MM + m] = pv[k] * inv;
    }
    __syncthreads();

    // phase B: agg[p][c][m] = sum_k f[k][c] * perm[k][m]  (thread = (point, 4 c's), bf16 gather)
    {
        int p = t >> 4;
        int cq = (t & 15) << 2;
        const unsigned short* fb = ftr + (size_t)b * (NNN * CC);
        float acc[4][MM];
        #pragma unroll
        for (int ci = 0; ci < 4; ++ci)
            #pragma unroll
            for (int m = 0; m < MM; ++m) acc[ci][m] = 0.f;
        int idxr[KK];
        #pragma unroll
        for (int k = 0; k < KK; ++k) idxr[k] = idx_lds[p * KK + k];
        #pragma unroll
        for (int k = 0; k < KK; ++k) {
            uint2 rv = *(const uint2*)(fb + idxr[k] * CC + cq);
            float fv[4];
            fv[0] = bflo2f(rv.x); fv[1] = bfhi2f(rv.x);
            fv[2] = bflo2f(rv.y); fv[3] = bfhi2f(rv.y);
            float4 pm0 = *(const float4*)&perm_lds[(p * KK + k) * MM];
            float4 pm1 = *(const float4*)&perm_lds[(p * KK + k) * MM + 4];
            float pvv[8] = {pm0.x, pm0.y, pm0.z, pm0.w, pm1.x, pm1.y, pm1.z, pm1.w};
            #pragma unroll
            for (int ci = 0; ci < 4; ++ci)
                #pragma unroll
                for (int m = 0; m < MM; ++m)
                    acc[ci][m] += fv[ci] * pvv[m];
        }
        #pragma unroll
        for (int ci = 0; ci < 4; ++ci) {
            union { bf16x8 v; unsigned short s[8]; } u;
            #pragma unroll
            for (int m = 0; m < MM; ++m) u.s[m] = f2bf(acc[ci][m]);
            *(bf16x8*)&aggA[p * 520 + (cq + ci) * MM] = u.v;
        }
    }
    __syncthreads();

    // phase C: out[p][o] = lrelu(agg[p][:] . W[o][:] + b[o]) + feature ; wave w -> o-tile
    {
        int w = t >> 6;
        int l = t & 63;
        int o0 = w << 4;
        int row = l & 15;        // A-row (point) and B-col (o)
        int kg = (l >> 4) << 3;  // k sub-offset within 32-chunk
        f32x4 acc = {0.f, 0.f, 0.f, 0.f};
        const unsigned short* wrow = Wb + (o0 + row) * CM;
        const unsigned short* arow = aggA + row * 520;
        #pragma unroll
        for (int s = 0; s < 16; ++s) {
            int k = s * 32 + kg;
            bf16x8 af = *(const bf16x8*)&arow[k];
            bf16x8 bfr = *(const bf16x8*)&wrow[k];
            acc = __builtin_amdgcn_mfma_f32_16x16x32_bf16(af, bfr, acc, 0, 0, 0);
        }
        int o = o0 + row;
        float bias = conv_b[o];
        const float* fres = feature + b * (CC * NNN) + o * NNN + n0;
        float* op = out + b * (OC * NNN) + o * NNN + n0;
        #pragma unroll
        for (int r = 0; r < 4; ++r) {
            int pt = ((l >> 4) << 2) + r;   // C/D: row = (lane>>4)*4 + reg
            float v = acc[r] + bias;
            v = v > 0.f ? v : v * 0.2f;
            op[pt] = v + fres[pt];
        }
    }
}

extern "C" void kernel_launch(void* const* d_in, const int* in_sizes, int n_in,
                              void* d_out, int out_size, void* d_ws, size_t ws_size,
                              hipStream_t stream) {
    const float* x        = (const float*)d_in[0];
    const float* feature  = (const float*)d_in[1];
    const int*   nidx     = (const int*)d_in[2];
    const float* kern     = (const float*)d_in[3];
    const float* conv_w   = (const float*)d_in[4];
    const float* conv_b   = (const float*)d_in[5];
    float* out = (float*)d_out;

    unsigned short* ftr = (unsigned short*)d_ws;                      // 4 MB: (B,N,C) bf16
    unsigned short* Wb  = (unsigned short*)((char*)d_ws + 4194304);   // 64 KB: bf16 W [o][k]

    prep_kernel<<<516, 256, 0, stream>>>(feature, conv_w, ftr, Wb);
    main_kernel<<<2048, 256, 0, stream>>>(x, feature, nidx, kern, conv_b, ftr, Wb, out);
}

// Round 3
// 106.711 us; speedup vs baseline: 1.0423x; 1.0277x over previous
//
#include <hip/hip_runtime.h>

#define BB 8
#define CC 64
#define NNN 4096
#define KK 20
#define MM 8
#define OC 64
#define CM 512

typedef __attribute__((ext_vector_type(8))) short bf16x8;
typedef __attribute__((ext_vector_type(4))) float f32x4;

__device__ __forceinline__ unsigned short f2bf(float f) {
    union { float f; unsigned int u; } v; v.f = f;
    unsigned int u = v.u;
    return (unsigned short)((u + 0x7FFFu + ((u >> 16) & 1u)) >> 16);
}
__device__ __forceinline__ float bfhi2f(unsigned int u) {
    union { unsigned int u; float f; } v; v.u = u & 0xffff0000u; return v.f;
}
__device__ __forceinline__ float bflo2f(unsigned int u) {
    union { unsigned int u; float f; } v; v.u = u << 16; return v.f;
}

// Kernel 1: transpose feature (B,C,N)->(B,N,C) bf16 into ws; conv_w -> bf16 [o][k]
__global__ __launch_bounds__(256) void prep_kernel(const float* __restrict__ feature,
                                                   const float* __restrict__ conv_w,
                                                   unsigned short* __restrict__ ftr,
                                                   unsigned short* __restrict__ Wb) {
    int blk = blockIdx.x;
    int t = threadIdx.x;
    if (blk < 512) {
        __shared__ float tile[64 * 65];
        int b = blk & 7;
        int n0 = (blk >> 3) << 6;
        const float* fb = feature + b * (CC * NNN);
        #pragma unroll
        for (int s = 0; s < 16; ++s) {
            int i = t + s * 256;
            int c = i >> 6, nn = i & 63;
            tile[c * 65 + nn] = fb[c * NNN + n0 + nn];
        }
        __syncthreads();
        unsigned short* fo = ftr + b * (NNN * CC) + n0 * CC;
        #pragma unroll
        for (int s = 0; s < 16; ++s) {
            int i = t + s * 256;
            int n = i >> 6, cc = i & 63;
            fo[n * CC + cc] = f2bf(tile[cc * 65 + n]);
        }
    } else {
        int base = (blk - 512) * 8192;
        #pragma unroll
        for (int s = 0; s < 32; ++s) {
            int i = base + t + s * 256;
            Wb[i] = f2bf(conv_w[i]);
        }
    }
}

// Kernel 2: 16 points/block; prefetch-overlapped phases; LDS overlay.
__global__ __launch_bounds__(256, 4) void main_kernel(
    const float* __restrict__ x,
    const float* __restrict__ feature,
    const int* __restrict__ nidx,
    const float* __restrict__ kern,
    const float* __restrict__ conv_b,
    const unsigned short* __restrict__ ftr,
    const unsigned short* __restrict__ Wb,
    float* __restrict__ out)
{
    // overlay: early-phase buffers are dead by the time aggA is written
    __shared__ __align__(16) union {
        struct {
            int   idx[16 * KK];          // 1280 B
            float xn[16 * KK * 3];       // 3840 B
            float perm[16 * KK * 10];    // 12800 B (stride 10: bank-conflict-free writes)
        } s;
        unsigned short aggA[16 * 520];   // 16640 B (pad 512->520)
    } u;

    int t = threadIdx.x;
    int blk = blockIdx.x;
    int b = blk & 7;                 // XCD-affinity swizzle
    int n0 = (blk >> 3) << 4;
    int w = t >> 6, l = t & 63;

    // ---- independent prefetches (issued before anything else) ----
    int o = (w << 4) + (l & 15);     // output channel for phase C / epilogue
    int pq = (l >> 4) << 2;          // point quad within the 16-point tile
    float4 fres4 = *(const float4*)(feature + ((size_t)b * CC + o) * NNN + n0 + pq);
    float bias = conv_b[o];
    int m_pre = t & 7;
    float kw0 = kern[m_pre], kw1 = kern[MM + m_pre], kw2 = kern[2 * MM + m_pre];

    // ---- stage neighbor indices ----
    const int* nb = nidx + (b * NNN + n0) * KK;
    for (int i = t; i < 16 * KK; i += 256) u.s.idx[i] = nb[i];
    __syncthreads();

    // ---- issue xyz gathers (regs), then ftr gathers (regs) ----
    const float* xb = x + b * (3 * NNN);
    float xreg[4];
    int xslot[4];
    #pragma unroll
    for (int s = 0; s < 4; ++s) {
        int i = t + s * 256;
        xslot[s] = i;
        if (i < 960) {
            int p2 = i / 60;
            int rem = i - p2 * 60;
            int k = rem / 3;
            int c = rem - k * 3;
            xreg[s] = xb[c * NNN + u.s.idx[p2 * KK + k]];
        }
    }

    int p = t >> 4;                  // point for phase B
    int cq = (t & 15) << 2;          // 4 channels for phase B
    const unsigned short* fb = ftr + (size_t)b * (NNN * CC);
    uint2 fr[KK];
    #pragma unroll
    for (int k = 0; k < KK; ++k)
        fr[k] = *(const uint2*)(fb + (size_t)u.s.idx[p * KK + k] * CC + cq);

    // commit xyz to LDS (waits only on the xyz loads; ftr stays in flight)
    #pragma unroll
    for (int s = 0; s < 4; ++s)
        if (xslot[s] < 960) u.s.xn[xslot[s]] = xreg[s];
    __syncthreads();

    // ---- phase A: permatrix + softmax over k (thread = (point, m)) ----
    if (t < 128) {
        int pp = t >> 3;
        int m = t & 7;
        const float* xp = &u.s.xn[pp * 60];
        float bx = xp[0], by = xp[1], bz = xp[2];
        float pv[KK];
        #pragma unroll
        for (int k = 0; k < KK; ++k) {
            float dx = xp[k * 3 + 0] - bx;
            float dy = xp[k * 3 + 1] - by;
            float dz = xp[k * 3 + 2] - bz;
            pv[k] = dx * kw0 + dy * kw1 + dz * kw2;
        }
        if (m == 0) pv[0] += 1.0f;
        float mx = pv[0];
        #pragma unroll
        for (int k = 1; k < KK; ++k) mx = fmaxf(mx, pv[k]);
        float sum = 0.f;
        #pragma unroll
        for (int k = 0; k < KK; ++k) { pv[k] = __expf(pv[k] - mx); sum += pv[k]; }
        float inv = 1.0f / sum;
        #pragma unroll
        for (int k = 0; k < KK; ++k) u.s.perm[(pp * KK + k) * 10 + m] = pv[k] * inv;
    }
    __syncthreads();

    // ---- phase B: agg[p][c][m] += f[k][c] * perm[k][m], f from prefetched regs ----
    float acc[4][MM];
    #pragma unroll
    for (int ci = 0; ci < 4; ++ci)
        #pragma unroll
        for (int m = 0; m < MM; ++m) acc[ci][m] = 0.f;
    #pragma unroll
    for (int k = 0; k < KK; ++k) {
        float fv[4];
        fv[0] = bflo2f(fr[k].x); fv[1] = bfhi2f(fr[k].x);
        fv[2] = bflo2f(fr[k].y); fv[3] = bfhi2f(fr[k].y);
        const float* pr = &u.s.perm[(p * KK + k) * 10];
        float2 q0 = *(const float2*)(pr + 0);
        float2 q1 = *(const float2*)(pr + 2);
        float2 q2 = *(const float2*)(pr + 4);
        float2 q3 = *(const float2*)(pr + 6);
        float pvv[8] = {q0.x, q0.y, q1.x, q1.y, q2.x, q2.y, q3.x, q3.y};
        #pragma unroll
        for (int ci = 0; ci < 4; ++ci)
            #pragma unroll
            for (int m = 0; m < MM; ++m)
                acc[ci][m] += fv[ci] * pvv[m];
    }
    __syncthreads();   // all perm reads done before aggA overlays it

    #pragma unroll
    for (int ci = 0; ci < 4; ++ci) {
        union { bf16x8 v; unsigned short s2[8]; } pk;
        #pragma unroll
        for (int m = 0; m < MM; ++m) pk.s2[m] = f2bf(acc[ci][m]);
        *(bf16x8*)&u.aggA[p * 520 + (cq + ci) * MM] = pk.v;
    }
    __syncthreads();

    // ---- phase C: (16 pts x 512) @ (512 x 16 o) per wave via MFMA + fused epilogue ----
    {
        int row = l & 15;
        int kg = (l >> 4) << 3;
        f32x4 acc2 = {0.f, 0.f, 0.f, 0.f};
        const unsigned short* wrow = Wb + (size_t)o * CM;
        const unsigned short* arow = u.aggA + row * 520;
        #pragma unroll
        for (int s = 0; s < 16; ++s) {
            int k = s * 32 + kg;
            bf16x8 af = *(const bf16x8*)&arow[k];
            bf16x8 bfr = *(const bf16x8*)&wrow[k];
            acc2 = __builtin_amdgcn_mfma_f32_16x16x32_bf16(af, bfr, acc2, 0, 0, 0);
        }
        float4 res;
        #pragma unroll
        for (int r = 0; r < 4; ++r) {
            float v = acc2[r] + bias;
            v = v > 0.f ? v : v * 0.2f;
            ((float*)&res)[r] = v + ((const float*)&fres4)[r];
        }
        *(float4*)(out + ((size_t)b * CC + o) * NNN + n0 + pq) = res;
    }
}

extern "C" void kernel_launch(void* const* d_in, const int* in_sizes, int n_in,
                              void* d_out, int out_size, void* d_ws, size_t ws_size,
                              hipStream_t stream) {
    const float* x        = (const float*)d_in[0];
    const float* feature  = (const float*)d_in[1];
    const int*   nidx     = (const int*)d_in[2];
    const float* kern     = (const float*)d_in[3];
    const float* conv_w   = (const float*)d_in[4];
    const float* conv_b   = (const float*)d_in[5];
    float* out = (float*)d_out;

    unsigned short* ftr = (unsigned short*)d_ws;                      // 4 MB: (B,N,C) bf16
    unsigned short* Wb  = (unsigned short*)((char*)d_ws + 4194304);   // 64 KB: bf16 W [o][k]

    prep_kernel<<<516, 256, 0, stream>>>(feature, conv_w, ftr, Wb);
    main_kernel<<<2048, 256, 0, stream>>>(x, feature, nidx, kern, conv_b, ftr, Wb, out);
}